// Round 12
// baseline (375.189 us; speedup 1.0000x reference)
//
#include <hip/hip_runtime.h>
#include <stdint.h>

typedef __attribute__((ext_vector_type(16))) float f32x16;
typedef __attribute__((ext_vector_type(8))) short bf16x8;

#define MFMA32 __builtin_amdgcn_mfma_f32_32x32x16_bf16

__device__ __forceinline__ unsigned short f2bf(float f) {
  union { float f; uint32_t u; } a; a.f = f;
  uint32_t u = a.u;
  uint32_t r = (u + 0x7FFFu + ((u >> 16) & 1u)) >> 16;
  return (unsigned short)r;
}

// Merged pack: quads 0..4194303 = A ([x|h] -> bf16 A[4096][4096]);
// quads 4194304..12582911 = W -> Wp[8192][4096], 32-col gate groups:
// packed row p: bn=p>>8, r=p&255; wn=r>>7, g=(r>>5)&3, hlow=r&31;
// hcol H = bn*64 + wn*32 + hlow; cols 0..2047 = Wx_g[H][:], 2048.. = Wh_g[H][:]
__global__ void pack_all_kernel(const float4* __restrict__ x, const float4* __restrict__ hh,
                                const float* __restrict__ Wii, const float* __restrict__ Wif,
                                const float* __restrict__ Wig, const float* __restrict__ Wio,
                                const float* __restrict__ Whi, const float* __restrict__ Whf,
                                const float* __restrict__ Whg, const float* __restrict__ Who,
                                ushort4* __restrict__ A, ushort4* __restrict__ Wp) {
  const int total = 12582912;
  for (int q = blockIdx.x * blockDim.x + threadIdx.x; q < total; q += gridDim.x * blockDim.x) {
    if (q < 4194304) {
      int row = q >> 10, cq = q & 1023;
      float4 v = (cq < 512) ? x[row * 512 + cq] : hh[row * 512 + (cq - 512)];
      ushort4 o; o.x = f2bf(v.x); o.y = f2bf(v.y); o.z = f2bf(v.z); o.w = f2bf(v.w);
      A[q] = o;
    } else {
      int wq = q - 4194304;
      int p = wq >> 10, kq = wq & 1023;
      int r = p & 255;
      int g = (r >> 5) & 3;
      int H = ((p >> 8) << 6) | ((r >> 7) << 5) | (r & 31);
      const float* src;
      if (kq < 512) src = (g == 0) ? Wii : (g == 1) ? Wif : (g == 2) ? Wig : Wio;
      else          src = (g == 0) ? Whi : (g == 1) ? Whf : (g == 2) ? Whg : Who;
      const float4 v = *(const float4*)&src[(size_t)H * 2048 + ((kq & 511) << 2)];
      ushort4 o; o.x = f2bf(v.x); o.y = f2bf(v.y); o.z = f2bf(v.z); o.w = f2bf(v.w);
      Wp[wq] = o;
    }
  }
}

// FAT-WAVE GEMM: 256x256 tile, BK=64, 4 waves (2Mx2N), per-wave 128x128,
// mfma_f32_32x32x16_bf16, acc = 16 x f32x16 (256 VGPR, 1 wave/SIMD).
// LDS: 2 bufs x (A 256x64 + B 256x64) = 128 KiB. Per tile: stage T+1 (16
// gloads) at top, 4 ks-steps software-pipelined (read ks+1 while MFMA ks),
// vmcnt(0)+barrier at end. XOR-chunk swizzle (phys = logical ^ (row&7)).
#define AS1 __attribute__((address_space(1)))
#define AS3 __attribute__((address_space(3)))
#define GLD(srcp, dstE)                                                         \
  __builtin_amdgcn_global_load_lds((const AS1 void*)(srcp),                     \
                                   (AS3 void*)(&smem[dstE]), 16, 0, 0)

#define STAGE(dstB_, kO_)                                                       \
  _Pragma("unroll") for (int j = 0; j < 8; ++j) {                               \
    GLD(aS + (size_t)j * 32768 + (kO_), (dstB_) + wA + j * 512);                \
    GLD(bS + (size_t)j * 32768 + (kO_), (dstB_) + 16384 + wA + j * 512);        \
  }

#define READK(bufE_, ks_, AF_, BF_)                                             \
  _Pragma("unroll") for (int mi = 0; mi < 4; ++mi)                              \
    AF_[mi] = *(const bf16x8*)&smem[(bufE_) + (aB ^ ((ks_) << 4)) + mi * 2048]; \
  _Pragma("unroll") for (int ni = 0; ni < 4; ++ni)                              \
    BF_[ni] = *(const bf16x8*)&smem[(bufE_) + (bB ^ ((ks_) << 4)) + ni * 2048];

#define COMP(AF_, BF_)                                                          \
  _Pragma("unroll") for (int mi = 0; mi < 4; ++mi)                              \
    _Pragma("unroll") for (int ni = 0; ni < 4; ++ni)                            \
      acc[mi][ni] = MFMA32(AF_[mi], BF_[ni], acc[mi][ni], 0, 0, 0);

#define TILE(bufE_, obufE_, kN_, DOST_)                                         \
  {                                                                             \
    bf16x8 aE[4], bE[4], aO[4], bO[4];                                          \
    if (DOST_) { STAGE(obufE_, kN_); }                                          \
    READK(bufE_, 0, aE, bE);                                                    \
    READK(bufE_, 1, aO, bO);                                                    \
    COMP(aE, bE);                                                               \
    READK(bufE_, 2, aE, bE);                                                    \
    COMP(aO, bO);                                                               \
    READK(bufE_, 3, aO, bO);                                                    \
    COMP(aE, bE);                                                               \
    COMP(aO, bO);                                                               \
    asm volatile("s_waitcnt vmcnt(0)" ::: "memory");                            \
    __builtin_amdgcn_s_barrier();                                               \
  }

__global__ __launch_bounds__(256, 1)
void lstm_gemm_kernel(const ushort* __restrict__ A, const ushort* __restrict__ Wp,
                      const float* __restrict__ c,
                      const float* __restrict__ bii, const float* __restrict__ bif_,
                      const float* __restrict__ big_, const float* __restrict__ bio_,
                      const float* __restrict__ bhi, const float* __restrict__ bhf,
                      const float* __restrict__ bhg, const float* __restrict__ bho,
                      float* __restrict__ out) {
  __shared__ ushort smem[65536];  // 2 bufs x 32768 elems (A 16K + B 16K elems)
  const int tid = threadIdx.x;
  const int lane = tid & 63, w = tid >> 6;   // 4 waves
  const int wm = w >> 1, wn = w & 1;
  const int wA = w * 4096;

  // bn-major XCD mapping: XCD x owns bn in [x*4, x*4+4) x all 16 bm.
  const int bid = blockIdx.x;
  const int xcd = bid & 7, qq = bid >> 3;
  const int bn = (xcd << 2) | (qq >> 4);
  const int bm = qq & 15;

  const int lane31 = lane & 31, hi = lane >> 5;
  // Fragment read bases (elems). Logical chunk for ks: 2*ks + hi; phys =
  // logical ^ (row&7); row = lane31 (+mi*32, bit>=6 of elems so XOR-safe).
  const int c0 = (hi ^ (lane & 7)) << 3;                 // elems
  const int aB = (wm * 128 + lane31) * 64 + c0;          // A region at 0
  const int bB = 16384 + (wn * 128 + lane31) * 64 + c0;  // B region at 16384

  // DMA staging: lane l -> row l>>3 (of 8), phys chunk l&7 holding logical
  // (l&7)^((l>>3)&7) -> pre-swizzled global source.
  const int chunkOff = ((lane & 7) ^ (lane >> 3)) << 3;
  const ushort* aS = A + (size_t)(bm * 256 + w * 64 + (lane >> 3)) * 4096 + chunkOff;
  const ushort* bS = Wp + (size_t)(bn * 256 + w * 64 + (lane >> 3)) * 4096 + chunkOff;

  f32x16 acc[4][4];
#pragma unroll
  for (int i = 0; i < 4; i++)
#pragma unroll
    for (int j = 0; j < 4; j++)
#pragma unroll
      for (int e = 0; e < 16; e++) acc[i][j][e] = 0.f;

  // Prologue: stage tile 0 into buf0.
  STAGE(0, 0);
  asm volatile("s_waitcnt vmcnt(0)" ::: "memory");
  __builtin_amdgcn_s_barrier();

#pragma unroll 1
  for (int T = 0; T < 62; T += 2) {
    TILE(0, 32768, (T + 1) * 64, true);
    TILE(32768, 0, (T + 2) * 64, true);
  }
  TILE(0, 32768, 63 * 64, true);   // T=62, stage 63
  TILE(32768, 0, 0, false);        // T=63

  // Fused LSTM epilogue. C/D layout (32x32): col=lane&31,
  // row=(reg&3)+8*(reg>>2)+4*(lane>>5). n-fragment index == gate.
  const int hcol = bn * 64 + wn * 32 + lane31;
  const float bI = bii[hcol] + bhi[hcol];
  const float bF = bif_[hcol] + bhf[hcol];
  const float bG = big_[hcol] + bhg[hcol];
  const float bO = bio_[hcol] + bho[hcol];
#pragma unroll
  for (int mi = 0; mi < 4; ++mi) {
    const int rb = bm * 256 + wm * 128 + mi * 32 + 4 * hi;
#pragma unroll
    for (int r = 0; r < 16; ++r) {
      const int row = rb + (r & 3) + 8 * (r >> 2);
      const float ii = acc[mi][0][r] + bI;
      const float ff = acc[mi][1][r] + bF;
      const float gg = acc[mi][2][r] + bG;
      const float oo = acc[mi][3][r] + bO;
      const float iv = 1.f / (1.f + __expf(-ii));
      const float fv = 1.f / (1.f + __expf(-ff));
      const float gv = tanhf(gg);
      const float ov = 1.f / (1.f + __expf(-oo));
      const float cv = c[(size_t)row * 2048 + hcol];
      const float cn = fv * cv + iv * gv;
      const float hn = ov * tanhf(cn);
      out[(size_t)row * 2048 + hcol] = hn;
      out[(size_t)8388608 + (size_t)row * 2048 + hcol] = cn;
    }
  }
}

extern "C" void kernel_launch(void* const* d_in, const int* in_sizes, int n_in,
                              void* d_out, int out_size, void* d_ws, size_t ws_size,
                              hipStream_t stream) {
  const float* x = (const float*)d_in[0];
  const float* h = (const float*)d_in[1];
  const float* c = (const float*)d_in[2];
  const float* Wii = (const float*)d_in[3];  const float* bii = (const float*)d_in[4];
  const float* Wif = (const float*)d_in[5];  const float* bif_ = (const float*)d_in[6];
  const float* Wig = (const float*)d_in[7];  const float* big_ = (const float*)d_in[8];
  const float* Wio = (const float*)d_in[9];  const float* bio_ = (const float*)d_in[10];
  const float* Whi = (const float*)d_in[11]; const float* bhi = (const float*)d_in[12];
  const float* Whf = (const float*)d_in[13]; const float* bhf = (const float*)d_in[14];
  const float* Whg = (const float*)d_in[15]; const float* bhg = (const float*)d_in[16];
  const float* Who = (const float*)d_in[17]; const float* bho = (const float*)d_in[18];

  ushort* Abf = (ushort*)d_ws;                    // 4096*4096 bf16
  ushort* Wpk = Abf + (size_t)4096 * 4096;        // 8192*4096 bf16
  float* out = (float*)d_out;

  pack_all_kernel<<<3072, 256, 0, stream>>>((const float4*)x, (const float4*)h,
                                            Wii, Wif, Wig, Wio, Whi, Whf, Whg, Who,
                                            (ushort4*)Abf, (ushort4*)Wpk);
  lstm_gemm_kernel<<<512, 256, 0, stream>>>(Abf, Wpk, c,
                                            bii, bif_, big_, bio_, bhi, bhf, bhg, bho, out);
}

// Round 13
// 305.053 us; speedup vs baseline: 1.2299x; 1.2299x over previous
//
#include <hip/hip_runtime.h>
#include <stdint.h>

typedef __attribute__((ext_vector_type(4))) float f32x4;
typedef __attribute__((ext_vector_type(8))) short bf16x8;

#define MFMA_BF16 __builtin_amdgcn_mfma_f32_16x16x32_bf16

__device__ __forceinline__ unsigned short f2bf(float f) {
  union { float f; uint32_t u; } a; a.f = f;
  uint32_t u = a.u;
  uint32_t r = (u + 0x7FFFu + ((u >> 16) & 1u)) >> 16;
  return (unsigned short)r;
}

// Merged pack: quads 0..4194303 = A ([x|h] -> bf16 A[4096][4096]);
// quads 4194304..12582911 = W (8 mats -> gate-interleaved Wp[8192][4096]).
// Packed row p (within 256-row bn panel): [half(2)][wn(4)][glow(2)][hlow(16)]
//   gate g = half*2+glow ; hcol H = bn*64 + wn*16 + hlow
__global__ void pack_all_kernel(const float4* __restrict__ x, const float4* __restrict__ hh,
                                const float* __restrict__ Wii, const float* __restrict__ Wif,
                                const float* __restrict__ Wig, const float* __restrict__ Wio,
                                const float* __restrict__ Whi, const float* __restrict__ Whf,
                                const float* __restrict__ Whg, const float* __restrict__ Who,
                                ushort4* __restrict__ A, ushort4* __restrict__ Wp) {
  const int total = 12582912;
  for (int q = blockIdx.x * blockDim.x + threadIdx.x; q < total; q += gridDim.x * blockDim.x) {
    if (q < 4194304) {
      int row = q >> 10, cq = q & 1023;
      float4 v = (cq < 512) ? x[row * 512 + cq] : hh[row * 512 + (cq - 512)];
      ushort4 o; o.x = f2bf(v.x); o.y = f2bf(v.y); o.z = f2bf(v.z); o.w = f2bf(v.w);
      A[q] = o;
    } else {
      int wq = q - 4194304;
      int p = wq >> 10, kq = wq & 1023;
      int r = p & 255;
      int g = ((r >> 7) << 1) | ((r >> 4) & 1);
      int H = ((p >> 8) << 6) | (((r >> 5) & 3) << 4) | (r & 15);
      const float* src;
      if (kq < 512) src = (g == 0) ? Wii : (g == 1) ? Wif : (g == 2) ? Wig : Wio;
      else          src = (g == 0) ? Whi : (g == 1) ? Whf : (g == 2) ? Whg : Who;
      const float4 v = *(const float4*)&src[(size_t)H * 2048 + ((kq & 511) << 2)];
      ushort4 o; o.x = f2bf(v.x); o.y = f2bf(v.y); o.z = f2bf(v.z); o.w = f2bf(v.w);
      Wp[wq] = o;
    }
  }
}

// 3-BARRIER TILE. 256x256, BK=64, 8 waves (2Mx4N), per-wave 128x64.
// LDS: 2 bufs x {A0,A1,B0,B1} halves. Per tile:
//   vmcnt(6); BAR | ph0: rd af0,b01; stg A1(T+1)->nbuf; q00 | BAR
//   ph1: rd b23; stg A0,B0(T+2)->buf; q01 | BAR
//   ph2: rd af1; stg B1(T+2)->buf; q10+q11
// Compiler inserts progressive counted lgkmcnt before MFMA operand use; the
// MFMA pipe backlog (~1240 cyc/SIMD) covers each read window. Barriers are
// asm memory fences so no memory op crosses them. WAR/RAW proofs in comments.
#define BARF asm volatile("s_barrier" ::: "memory")

#define STGH(srcH, kOff, dstE)                                                  \
  __builtin_amdgcn_global_load_lds(                                             \
      (const __attribute__((address_space(1))) void*)((srcH) + (kOff)),         \
      (__attribute__((address_space(3))) void*)(&smem[dstE]), 16, 0, 0);        \
  __builtin_amdgcn_global_load_lds(                                             \
      (const __attribute__((address_space(1))) void*)((srcH) + 32768 + (kOff)), \
      (__attribute__((address_space(3))) void*)(&smem[(dstE) + 512]), 16, 0, 0)

#define Q(ACCR, ACCC, AF_, BF_)                                                 \
  _Pragma("unroll") for (int kk = 0; kk < 2; ++kk)                              \
    _Pragma("unroll") for (int m = 0; m < 4; ++m)                               \
      _Pragma("unroll") for (int n = 0; n < 2; ++n)                             \
        acc[(ACCR) + m][(ACCC) + n] =                                           \
            MFMA_BF16(AF_[m][kk], BF_[n][kk], acc[(ACCR) + m][(ACCC) + n], 0, 0, 0);

#define TILE(bufE_, nbufE_, kA1_, kT2_, ST_A1, ST_T2, VMC)                       \
  {                                                                              \
    if ((VMC) == 6) asm volatile("s_waitcnt vmcnt(6)" ::: "memory");             \
    else            asm volatile("s_waitcnt vmcnt(0)" ::: "memory");             \
    BARF;  /* all waves' tile-T halves DMA-visible */                            \
    bf16x8 af0[4][2], af1[4][2], b01[2][2], b23[2][2];                           \
    /* ph0 */                                                                    \
    _Pragma("unroll") for (int m = 0; m < 4; ++m) {                              \
      af0[m][0] = *(const bf16x8*)&smem[(bufE_) + aR + m * 1024 + colE0];        \
      af0[m][1] = *(const bf16x8*)&smem[(bufE_) + aR + m * 1024 + colE1];        \
    }                                                                            \
    _Pragma("unroll") for (int n = 0; n < 2; ++n) {                              \
      b01[n][0] = *(const bf16x8*)&smem[(bufE_) + 16384 + bR + n * 1024 + colE0];\
      b01[n][1] = *(const bf16x8*)&smem[(bufE_) + 16384 + bR + n * 1024 + colE1];\
    }                                                                            \
    if (ST_A1) { STGH(aSrcH1, kA1_, (nbufE_) + 8192 + dstW); }                   \
    __builtin_amdgcn_s_setprio(1);                                               \
    Q(0, 0, af0, b01);                                                           \
    __builtin_amdgcn_s_setprio(0);                                               \
    BARF;  /* ph0 reads done (consumed) -> safe to restage A0,B0 */              \
    /* ph1 */                                                                    \
    _Pragma("unroll") for (int n = 0; n < 2; ++n) {                              \
      b23[n][0] = *(const bf16x8*)&smem[(bufE_) + 24576 + bR + n * 1024 + colE0];\
      b23[n][1] = *(const bf16x8*)&smem[(bufE_) + 24576 + bR + n * 1024 + colE1];\
    }                                                                            \
    if (ST_T2) {                                                                 \
      STGH(aSrcH0, kT2_, (bufE_) + dstW);                                        \
      STGH(bSrcH0, kT2_, (bufE_) + 16384 + dstW);                                \
    }                                                                            \
    __builtin_amdgcn_s_setprio(1);                                               \
    Q(0, 2, af0, b23);                                                           \
    __builtin_amdgcn_s_setprio(0);                                               \
    BARF;  /* ph1 reads done -> safe to restage B1 */                            \
    /* ph2 */                                                                    \
    _Pragma("unroll") for (int m = 0; m < 4; ++m) {                              \
      af1[m][0] = *(const bf16x8*)&smem[(bufE_) + 8192 + aR + m * 1024 + colE0]; \
      af1[m][1] = *(const bf16x8*)&smem[(bufE_) + 8192 + aR + m * 1024 + colE1]; \
    }                                                                            \
    if (ST_T2) { STGH(bSrcH1, kT2_, (bufE_) + 24576 + dstW); }                   \
    __builtin_amdgcn_s_setprio(1);                                               \
    Q(4, 0, af1, b01);                                                           \
    Q(4, 2, af1, b23);                                                           \
    __builtin_amdgcn_s_setprio(0);                                               \
  }

__global__ __launch_bounds__(512, 2)
void lstm_gemm_kernel(const ushort* __restrict__ A, const ushort* __restrict__ Wp,
                      const float* __restrict__ c,
                      const float* __restrict__ bii, const float* __restrict__ bif_,
                      const float* __restrict__ big_, const float* __restrict__ bio_,
                      const float* __restrict__ bhi, const float* __restrict__ bhf,
                      const float* __restrict__ bhg, const float* __restrict__ bho,
                      float* __restrict__ out) {
  __shared__ ushort smem[65536];  // 2 bufs x {A0,A1,B0,B1} halves x 16 KiB = 128 KiB
  const int tid = threadIdx.x;
  const int lane = tid & 63, w = tid >> 6;
  const int wm = w >> 2, wn = w & 3;

  // bn-major XCD mapping: XCD x owns bn in [x*4, x*4+4) x all 16 bm.
  const int bid = blockIdx.x;
  const int xcd = bid & 7, qq = bid >> 3;
  const int bn = (xcd << 2) | (qq >> 4);
  const int bm = qq & 15;

  const int laneRow = lane & 15, lane16 = lane >> 4;
  const int lr7 = laneRow & 7;
  const int colE0 = (lane16 ^ lr7) << 3;         // elem offset within 64-el row, kk=0
  const int colE1 = ((4 + lane16) ^ lr7) << 3;   // kk=1

  // DMA: lane l -> half-row (l>>3), phys chunk l&7 holding logical chunk
  // (l&7)^((l>>3)&7) -> pre-swizzled global source (proven 0-conflict scheme).
  const int chunkOff = ((lane & 7) ^ (lane >> 3)) << 3;
  const ushort* aSrcH0 = A + (size_t)(bm * 256 + 16 * w + (lane >> 3)) * 4096 + chunkOff;
  const ushort* aSrcH1 = aSrcH0 + (size_t)128 * 4096;
  const ushort* bSrcH0 = Wp + (size_t)(bn * 256 + 16 * w + (lane >> 3)) * 4096 + chunkOff;
  const ushort* bSrcH1 = bSrcH0 + (size_t)128 * 4096;
  const int dstW = w * 1024;  // wave's 16 rows within a half

  const int aR = (wm * 64 + laneRow) * 64;   // + buf + half + m*1024 + colE
  const int bR = (wn * 32 + laneRow) * 64;   // + buf + half + n*1024 + colE

  f32x4 acc[8][4];
#pragma unroll
  for (int i = 0; i < 8; i++)
#pragma unroll
    for (int j = 0; j < 4; j++) acc[i][j] = (f32x4){0.f, 0.f, 0.f, 0.f};

  // Prologue: T0 all 4 halves (8 loads) then T1's A0,B0,B1 (6 loads).
  // First TILE's vmcnt(6) completes exactly T0's 8.
  STGH(aSrcH0, 0, dstW);                  // A0(0)
  STGH(bSrcH0, 0, 16384 + dstW);          // B0(0)
  STGH(bSrcH1, 0, 24576 + dstW);          // B1(0)
  STGH(aSrcH1, 0, 8192 + dstW);           // A1(0)
  STGH(aSrcH0, 64, 32768 + dstW);         // A0(1)
  STGH(bSrcH0, 64, 32768 + 16384 + dstW); // B0(1)
  STGH(bSrcH1, 64, 32768 + 24576 + dstW); // B1(1)

#pragma unroll 1
  for (int T = 0; T < 62; T += 2) {
    const int kA = (T + 1) << 6, kB = (T + 2) << 6, kC = (T + 3) << 6;
    TILE(0, 32768, kA, kB, true, true, 6);
    TILE(32768, 0, kB, kC, true, true, 6);
  }
  TILE(0, 32768, 63 << 6, 0, true, false, 6);   // T=62: stage A1(63) only
  TILE(32768, 0, 0, 0, false, false, 0);        // T=63: drain

  // Fused LSTM epilogue: acc[mi][gate][rr] register-local per (row, hcol).
  const int hcol = bn * 64 + wn * 16 + laneRow;
  const float bI = bii[hcol] + bhi[hcol];
  const float bF = bif_[hcol] + bhf[hcol];
  const float bG = big_[hcol] + bhg[hcol];
  const float bO = bio_[hcol] + bho[hcol];
#pragma unroll
  for (int mi = 0; mi < 8; ++mi) {
    const int rowBase = bm * 256 + (mi >> 2) * 128 + wm * 64 + (mi & 3) * 16 + lane16 * 4;
#pragma unroll
    for (int rr = 0; rr < 4; ++rr) {
      const int row = rowBase + rr;
      const float ii = acc[mi][0][rr] + bI;
      const float ff = acc[mi][1][rr] + bF;
      const float gg = acc[mi][2][rr] + bG;
      const float oo = acc[mi][3][rr] + bO;
      const float iv = 1.f / (1.f + __expf(-ii));
      const float fv = 1.f / (1.f + __expf(-ff));
      const float gv = tanhf(gg);
      const float ov = 1.f / (1.f + __expf(-oo));
      const float cv = c[(size_t)row * 2048 + hcol];
      const float cn = fv * cv + iv * gv;
      const float hn = ov * tanhf(cn);
      out[(size_t)row * 2048 + hcol] = hn;
      out[(size_t)8388608 + (size_t)row * 2048 + hcol] = cn;
    }
  }
}

extern "C" void kernel_launch(void* const* d_in, const int* in_sizes, int n_in,
                              void* d_out, int out_size, void* d_ws, size_t ws_size,
                              hipStream_t stream) {
  const float* x = (const float*)d_in[0];
  const float* h = (const float*)d_in[1];
  const float* c = (const float*)d_in[2];
  const float* Wii = (const float*)d_in[3];  const float* bii = (const float*)d_in[4];
  const float* Wif = (const float*)d_in[5];  const float* bif_ = (const float*)d_in[6];
  const float* Wig = (const float*)d_in[7];  const float* big_ = (const float*)d_in[8];
  const float* Wio = (const float*)d_in[9];  const float* bio_ = (const float*)d_in[10];
  const float* Whi = (const float*)d_in[11]; const float* bhi = (const float*)d_in[12];
  const float* Whf = (const float*)d_in[13]; const float* bhf = (const float*)d_in[14];
  const float* Whg = (const float*)d_in[15]; const float* bhg = (const float*)d_in[16];
  const float* Who = (const float*)d_in[17]; const float* bho = (const float*)d_in[18];

  ushort* Abf = (ushort*)d_ws;                    // 4096*4096 bf16
  ushort* Wpk = Abf + (size_t)4096 * 4096;        // 8192*4096 bf16
  float* out = (float*)d_out;

  pack_all_kernel<<<3072, 256, 0, stream>>>((const float4*)x, (const float4*)h,
                                            Wii, Wif, Wig, Wio, Whi, Whf, Whg, Who,
                                            (ushort4*)Abf, (ushort4*)Wpk);
  lstm_gemm_kernel<<<512, 512, 0, stream>>>(Abf, Wpk, c,
                                            bii, bif_, big_, bio_, bhi, bhf, bhg, bho, out);
}